// Round 7
// baseline (374.156 us; speedup 1.0000x reference)
//
#include <hip/hip_runtime.h>

// AnomalyAttention: B=16, L=512, H=8, E=D=64. f32 in/out, bf16 MFMA compute.
// Transposed formulation: S^T = K.Q^T (D: row=s, col=l), out^T = V^T.W^T.
// R9: prior p computed directly in B-operand layout per lane. Uniform
// 8-iteration loop (R5). R12: T14 issue-early/write-late prefetch, no
// loop-carried staging regs, launch_bounds(256,3), t reversed. R15: K/V
// double-buffer, ONE barrier/iter (neutral -> barrier count exonerated).
// R16 (KILL the We LDS round-trip): QK's 16x16 D-layout gives lane (c,q)
//   e[s=nt*16+q*4+r][l=c] -- groups of 4 s. PV previously needed groups of 8
//   (16x16x32 B-operand), forcing a ds_write -> lgkmcnt(0) -> ds_read
//   redistribution every live iteration (2 serialized LDS latencies + a hard
//   mid-iteration drain). v_mfma_f32_16x16x16_bf16's B-operand wants EXACTLY
//   groups of 4: B[k=q*4+j][n=c] == QK D-layout. PV now consumes exp'd scores
//   straight from registers; p computed per-16-chunk in the same layout.
//   We array deleted (-9KB LDS -> 36.9KB), zero-fills deleted, both mid-loop
//   lgkm drains deleted. V frags: one ds_read_b64 per (nd,nt): granule
//   G=2nt+(q>>1), dwords 2(q&1)+{0,1} -> shorts d*VST + ((G^(d>>3))<<3)
//   + (q&1)*4 (same granule-swizzled Vlds layout, same total bytes).
//   Per-16-chunk prior band: delta+16nt in [-79,79] (underflow-exact outside).
// Ledger: R10/R11 loop-carried staging spills at 128-reg cap; R13/R14 paired
//   512-thread blocks halve residency via regs; R12/R15 prefetch+dbuf neutral
//   -> load latency, barriers exonerated; chain is the remaining suspect.
// out = [ g*(e@V)/E + (1-g)*(p@V)/(P+1e-8) ] / (Sf+1e-8); E,P = sums of
// truncated-bf16 e,p (exactly the MFMA operands).

#define B_ 16
#define L_ 512
#define H_ 8
#define KST 72   // K LDS row stride (shorts)
#define VST 72   // V^T LDS row stride (shorts)

typedef __attribute__((ext_vector_type(8))) short bf16x8;
typedef __attribute__((ext_vector_type(4))) short bf16x4;
typedef __attribute__((ext_vector_type(4))) float f32x4;
union FR { bf16x8 v; unsigned u[4]; uint4 q4; };
union F2 { bf16x4 v; unsigned u[2]; };

static __device__ __forceinline__ unsigned fbits(float x){union{float f;unsigned u;}c;c.f=x;return c.u;}
static __device__ __forceinline__ float tvf(float x){union{unsigned u;float f;}c;c.u=fbits(x)&0xFFFF0000u;return c.f;}
// pack trunc-bf16(a) | trunc-bf16(b)<<16 in one v_perm_b32
static __device__ __forceinline__ unsigned pk2(float a,float b){return __builtin_amdgcn_perm(fbits(b),fbits(a),0x07060302u);}

#if defined(__has_builtin)
#if __has_builtin(__builtin_amdgcn_mfma_f32_16x16x16bf16_1k)
#define HAVE_MFMA16 1
#endif
#endif

// D = A*B + C, 16x16x16 bf16. A: lane holds A[m=lane&15][k=(lane>>4)*4+j];
// B: lane holds B[k=(lane>>4)*4+j][n=lane&15]; D: col=lane&15, row=(lane>>4)*4+r.
static __device__ __forceinline__ f32x4 mfma16(bf16x4 a, bf16x4 b, f32x4 c){
#ifdef HAVE_MFMA16
  return __builtin_amdgcn_mfma_f32_16x16x16bf16_1k(a,b,c,0,0,0);
#else
  // s_nop covers VALU-write -> MFMA-read hazard (compiler can't see into asm)
  asm volatile("s_nop 1\n\tv_mfma_f32_16x16x16_bf16 %0, %1, %2, %0"
               : "+v"(c) : "v"(a), "v"(b));
  return c;
#endif
}

// Block barrier with LDS-drain only: does NOT wait vmcnt, so register-staged
// global prefetch loads remain in flight across it (T4).
static __device__ __forceinline__ void barrier_lgkm(){
  asm volatile("s_waitcnt lgkmcnt(0)" ::: "memory");
  __builtin_amdgcn_s_barrier();
  asm volatile("" ::: "memory");
}

__global__ __launch_bounds__(256,3) void anomaly_attn(
    const float* __restrict__ Q, const float* __restrict__ K,
    const float* __restrict__ V, const float* __restrict__ Sig,
    const float* __restrict__ Gate, float* __restrict__ Out)
{
  __shared__ unsigned short Klds[2][64*KST];   // 18432 B (double-buffered)
  __shared__ unsigned short Vlds[2][64*VST];   // 18432 B (V^T, granule-swizzled)

  const int tid=threadIdx.x, lane=tid&63, wid=tid>>6, q=lane>>4, c=lane&15;
  const int idx=blockIdx.x, bh=idx&127, t=7-(idx>>7), h=bh&7, b=bh>>3;
  const int l0w = t*64 + wid*16;            // wave's 16 l-rows: l = l0w + c
  const size_t bh_off = ((size_t)b*L_*H_ + h)*64;
  const float* __restrict__ Qb=Q+bh_off;
  const float* __restrict__ Kb=K+bh_off;
  const float* __restrict__ Vb=V+bh_off;

  const int kr=tid>>2, kcb=tid&3, srp=tid>>3, scb=tid&7;
  const int gp=(srp>>2)^scb, rpl=srp&3, vb0i=(gp<<3);  // V pack mapping

  // per-thread staging base pointers (add s0*512 per tile)
  const float* __restrict__ vbase = Vb + (size_t)(2*srp)*512 + scb*8;
  const float* __restrict__ kbase = Kb + (size_t)kr*512 + kcb*16;

  // ---- prologue: load + pack tile 0 into buffer 0 (always live) ----
  {
    float4 a0=((const float4*)vbase)[0],       a1=((const float4*)vbase)[1];
    float4 b0=((const float4*)(vbase+512))[0], b1=((const float4*)(vbase+512))[1];
    float4 ka=((const float4*)kbase)[0], kb2=((const float4*)kbase)[1];
    float4 kc2=((const float4*)kbase)[2], kd2=((const float4*)kbase)[3];
    ((unsigned*)&Vlds[0][(scb*8+0)*VST+vb0i])[rpl]=pk2(a0.x,b0.x);
    ((unsigned*)&Vlds[0][(scb*8+1)*VST+vb0i])[rpl]=pk2(a0.y,b0.y);
    ((unsigned*)&Vlds[0][(scb*8+2)*VST+vb0i])[rpl]=pk2(a0.z,b0.z);
    ((unsigned*)&Vlds[0][(scb*8+3)*VST+vb0i])[rpl]=pk2(a0.w,b0.w);
    ((unsigned*)&Vlds[0][(scb*8+4)*VST+vb0i])[rpl]=pk2(a1.x,b1.x);
    ((unsigned*)&Vlds[0][(scb*8+5)*VST+vb0i])[rpl]=pk2(a1.y,b1.y);
    ((unsigned*)&Vlds[0][(scb*8+6)*VST+vb0i])[rpl]=pk2(a1.z,b1.z);
    ((unsigned*)&Vlds[0][(scb*8+7)*VST+vb0i])[rpl]=pk2(a1.w,b1.w);
    uint4 w0,w1;
    w0.x=pk2(ka.x,ka.y);   w0.y=pk2(ka.z,ka.w);
    w0.z=pk2(kb2.x,kb2.y); w0.w=pk2(kb2.z,kb2.w);
    w1.x=pk2(kc2.x,kc2.y); w1.y=pk2(kc2.z,kc2.w);
    w1.z=pk2(kd2.x,kd2.y); w1.w=pk2(kd2.z,kd2.w);
    uint4* dst=(uint4*)&Klds[0][kr*KST + kcb*16];
    dst[0]=w0; dst[1]=w1;
  }

  // ---- Q as B-operand frag: lane c -> l, quad*8+j -> e (for 16x16x32 QK) ----
  bf16x8 qf[2];
  {
    const float* qrow = Qb + (size_t)(l0w+c)*512;
    #pragma unroll
    for (int ks=0; ks<2; ++ks) {
      const float4 a = *(const float4*)(qrow + ks*32 + q*8);
      const float4 d4 = *(const float4*)(qrow + ks*32 + q*8 + 4);
      FR f;
      f.u[0]=pk2(a.x,a.y);  f.u[1]=pk2(a.z,a.w);
      f.u[2]=pk2(d4.x,d4.y); f.u[3]=pk2(d4.z,d4.w);
      qf[ks]=f.v;
    }
  }

  // ---- per-lane prior constants (row l = l0w + c) ----
  const float sgv = Sig[((size_t)b*L_ + l0w + c)*H_ + h];
  float sg = 1.f/(1.f+__expf(-5.f*sgv)) + 1e-5f;
  sg = exp2f(sg*1.5849625007211562f) - 1.f;          // 3^sg - 1
  const float invs = 0.3989422804014327f/sg;
  const float i2s2 = (0.5f/(sg*sg))*1.44269504088896f;

  float eP=0.f, pP=0.f;
  f32x4 accA[4], accB[4];
  #pragma unroll
  for (int n=0;n<4;++n){accA[n]=(f32x4)0.f;accB[n]=(f32x4)0.f;}

  barrier_lgkm();   // publish tile-0 buffers

  const int qh=q>>1, ql=(q&1)<<2;   // V b64 frag: granule half / dword pair

  for (int tile=0; tile<8; ++tile) {
    const int s0=tile*64, p=tile&1;
    const unsigned short* __restrict__ Krd=&Klds[p][0];
    const unsigned short* __restrict__ Vrd=&Vlds[p][0];
    const bool live = tile<=t, diag = tile==t;   // block-uniform
    const int delta = s0 - l0w;                  // wave-uniform

    // ---- issue tile+1 global loads NOW (within-iteration liveness, no
    //      loop-carried PHIs); consumed only at the pack below ----
    float4 sva0,sva1,svb0,svb1,ska,skb,skc,skd;
    bool live1=false, vneed1=false;
    if (tile<7) {
      const int d1=delta+64;
      live1 = (tile+1)<=t;
      const bool b0n = (d1    >= -95) && (d1    <= 79);
      const bool b1n = (d1+32 >= -95) && (d1+32 <= 79);
      vneed1 = live1 || b0n || b1n;              // block-uniform in value
      const float* vp = vbase + (size_t)(s0+64)*512;
      const float* kp = kbase + (size_t)(s0+64)*512;
      if (vneed1) {
        sva0=((const float4*)vp)[0];       sva1=((const float4*)vp)[1];
        svb0=((const float4*)(vp+512))[0]; svb1=((const float4*)(vp+512))[1];
      }
      if (live1) {
        ska=((const float4*)kp)[0]; skb=((const float4*)kp)[1];
        skc=((const float4*)kp)[2]; skd=((const float4*)kp)[3];
      }
    }
    asm volatile("" ::: "memory");   // pin prefetch issue before compute

    // ---- e path: S^T scores, exp -> ef frags IN REGISTERS (16x16x16 B layout
    //      == QK D layout: lane (c,q) owns s = nt*16+q*4+r for l=c) ----
    int ntmax = -1;
    F2 efv[4];
    if (live) {
      ntmax = diag ? wid : 3;                   // s-chunks with any e!=0
      f32x4 sacc[4];
      #pragma unroll
      for (int nt=0;nt<4;++nt) if (nt<=ntmax) {
        f32x4 s=(f32x4)0.f;
        #pragma unroll
        for (int ks=0;ks<2;++ks){
          const bf16x8 kf=*(const bf16x8*)&Krd[(nt*16+c)*KST + ks*32 + q*8];
          s=__builtin_amdgcn_mfma_f32_16x16x32_bf16(kf,qf[ks],s,0,0,0); // A=K(m=s),B=Q(n=l)
        }
        sacc[nt]=s;
      }
      #pragma unroll
      for (int nt=0;nt<4;++nt) if (nt<=ntmax) {
        float ev[4];
        #pragma unroll
        for (int r=0;r<4;++r) ev[r]=exp2f(sacc[nt][r]*0.180336880110323f); // exp(s/8)
        if (diag && nt==wid) {                   // per-element causal mask
          #pragma unroll
          for (int r=0;r<4;++r) if (4*q+r > c) ev[r]=0.f;
        }
        #pragma unroll
        for (int r=0;r<4;++r) eP += tvf(ev[r]);  // sum == MFMA operand
        efv[nt].u[0]=pk2(ev[0],ev[1]); efv[nt].u[1]=pk2(ev[2],ev[3]);
      }
    }

    // ---- PV: A = V^T (m=d, k=s), B = e/p frags (k=s=nt*16+q*4+j, n=l=c).
    //      One ds_read_b64 per (nd,nt); no LDS round-trip, no zero-fill. ----
    #pragma unroll
    for (int nt=0;nt<4;++nt) {
      const bool ea = live && (nt<=ntmax);
      const int dw = delta + nt*16;
      const bool pa = (dw >= -79) && (dw <= 79); // per-16-chunk prior band
      if (ea || pa) {
        F2 pfv;
        if (pa) {
          float pv[4];
          #pragma unroll
          for (int j=0;j<4;++j){
            const float dd=(float)(c - nt*16 - q*4 - j - delta);  // l - s
            pv[j]=invs*exp2f(-dd*dd*i2s2);
            pP += tvf(pv[j]);
          }
          pfv.u[0]=pk2(pv[0],pv[1]); pfv.u[1]=pk2(pv[2],pv[3]);
        }
        #pragma unroll
        for (int nd=0;nd<4;++nd){
          const int d=nd*16+c;
          const int graw=(2*nt+qh)^(d>>3);
          const bf16x4 vf=*(const bf16x4*)&Vrd[d*VST + (graw<<3) + ql];
          if (ea) accA[nd]=mfma16(vf,efv[nt].v,accA[nd]);
          if (pa) accB[nd]=mfma16(vf,pfv.v,accB[nd]);
        }
      }
    }

    // ---- write-late: pack tile+1 into the OTHER buffer (no reader this
    //      iteration; vmcnt wait lands here, covered by the compute above) ----
    if (tile<7) {
      const int pn=p^1;
      if (vneed1) {
        ((unsigned*)&Vlds[pn][(scb*8+0)*VST+vb0i])[rpl]=pk2(sva0.x,svb0.x);
        ((unsigned*)&Vlds[pn][(scb*8+1)*VST+vb0i])[rpl]=pk2(sva0.y,svb0.y);
        ((unsigned*)&Vlds[pn][(scb*8+2)*VST+vb0i])[rpl]=pk2(sva0.z,svb0.z);
        ((unsigned*)&Vlds[pn][(scb*8+3)*VST+vb0i])[rpl]=pk2(sva0.w,svb0.w);
        ((unsigned*)&Vlds[pn][(scb*8+4)*VST+vb0i])[rpl]=pk2(sva1.x,svb1.x);
        ((unsigned*)&Vlds[pn][(scb*8+5)*VST+vb0i])[rpl]=pk2(sva1.y,svb1.y);
        ((unsigned*)&Vlds[pn][(scb*8+6)*VST+vb0i])[rpl]=pk2(sva1.z,svb1.z);
        ((unsigned*)&Vlds[pn][(scb*8+7)*VST+vb0i])[rpl]=pk2(sva1.w,svb1.w);
      }
      if (live1) {
        uint4 w0,w1;
        w0.x=pk2(ska.x,ska.y); w0.y=pk2(ska.z,ska.w);
        w0.z=pk2(skb.x,skb.y); w0.w=pk2(skb.z,skb.w);
        w1.x=pk2(skc.x,skc.y); w1.y=pk2(skc.z,skc.w);
        w1.z=pk2(skd.x,skd.y); w1.w=pk2(skd.z,skd.w);
        uint4* dst=(uint4*)&Klds[pn][kr*KST + kcb*16];
        dst[0]=w0; dst[1]=w1;
      }
    }

    barrier_lgkm();   // single per-iteration barrier: publishes tile+1 packs;
                      // orders this tile's LDS reads before next-next overwrite
  }

  // ---- epilogue: quad reduce, per-lane scalars, float4 stores ----
  eP += __shfl_xor(eP,16,64); eP += __shfl_xor(eP,32,64);
  pP += __shfl_xor(pP,16,64); pP += __shfl_xor(pP,32,64);
  float g=Gate[h]; g=1.f/(1.f+__expf(-g));
  const float cA=g/eP;                       // E>0 (diagonal always live)
  const float cB=(1.f-g)/(pP+1e-8f);
  const float Sf=g+(1.f-g)*(pP/(pP+1e-8f));
  const float nf=1.f/(Sf+1e-8f);
  #pragma unroll
  for (int nd=0;nd<4;++nd){
    float4 o;
    o.x=(cA*accA[nd][0]+cB*accB[nd][0])*nf;
    o.y=(cA*accA[nd][1]+cB*accB[nd][1])*nf;
    o.z=(cA*accA[nd][2]+cB*accB[nd][2])*nf;
    o.w=(cA*accA[nd][3]+cB*accB[nd][3])*nf;
    *(float4*)&Out[bh_off + (size_t)(l0w+c)*512 + nd*16 + 4*q] = o;
  }
}

extern "C" void kernel_launch(void* const* d_in, const int* in_sizes, int n_in,
                              void* d_out, int out_size, void* d_ws, size_t ws_size,
                              hipStream_t stream) {
    const float* Q    = (const float*)d_in[0];
    const float* K    = (const float*)d_in[1];
    const float* V    = (const float*)d_in[2];
    const float* Sig  = (const float*)d_in[3];
    const float* Gate = (const float*)d_in[4];
    // d_in[5] = attn_mask: deterministic causal triu — not read.
    float* Out = (float*)d_out;

    dim3 grid(8 * B_ * H_);   // 1024 blocks: bh = idx&127 (XCD-affine), t reversed
    anomaly_attn<<<grid, 256, 0, stream>>>(Q, K, V, Sig, Gate, Out);
}

// Round 8
// 192.781 us; speedup vs baseline: 1.9408x; 1.9408x over previous
//
#include <hip/hip_runtime.h>

// AnomalyAttention: B=16, L=512, H=8, E=D=64. f32 in/out, bf16 MFMA compute.
// Transposed formulation: S^T = K.Q^T (D: row=s, col=l), out^T = V^T.W^T.
// R9: prior p computed directly in B-operand layout per lane. Uniform
// 8-iteration loop (R5). R12: T14 issue-early/write-late prefetch, no
// loop-carried staging regs, launch_bounds(256,3), t reversed. R15: K/V
// double-buffer, ONE barrier/iter.
// R16 established (passed, same absmax): QK's 16x16 D-layout == 16x16x16
//   PV B-layout (lane (c,q) owns s=nt*16+q*4+r for l=c) -> PV can consume
//   exp'd scores straight from registers, deleting the We LDS round-trip.
//   But R16's IMPLEMENTATION spilled (~706MB scratch writes, 290us): either
//   the inline-asm mfma fallback (asm "+v" tuples pin acc in arch VGPRs,
//   spill-reload per call, AGPR half unused) or the F2 union ARRAY defeating
//   SROA. R17 fixes both: Path A uses the _1k BUILTIN only (acc stays
//   AGPR-allocatable) + plain unsigned[4][2] array with static indices +
//   bit_cast (no union aggregates). Path B (builtin absent) reverts the
//   compute section to R15's verified We-LDS form. No asm MFMA anywhere.
//   LDS_Block_Size tells which path compiled: 36864=A, 46080=B.
// out = [ g*(e@V)/E + (1-g)*(p@V)/(P+1e-8) ] / (Sf+1e-8); E,P = sums of
// truncated-bf16 e,p (exactly the MFMA operands).

#define B_ 16
#define L_ 512
#define H_ 8
#define KST 72   // K LDS row stride (shorts)
#define VST 72   // V^T LDS row stride (shorts)
#define WST 36   // We LDS row stride (dwords), 16 rows/wave (Path B only)

typedef __attribute__((ext_vector_type(8))) short bf16x8;
typedef __attribute__((ext_vector_type(4))) short bf16x4;
typedef __attribute__((ext_vector_type(4))) float f32x4;
union FR { bf16x8 v; unsigned u[4]; uint4 q4; };

static __device__ __forceinline__ unsigned fbits(float x){union{float f;unsigned u;}c;c.f=x;return c.u;}
static __device__ __forceinline__ float tvf(float x){union{unsigned u;float f;}c;c.u=fbits(x)&0xFFFF0000u;return c.f;}
// pack trunc-bf16(a) | trunc-bf16(b)<<16 in one v_perm_b32
static __device__ __forceinline__ unsigned pk2(float a,float b){return __builtin_amdgcn_perm(fbits(b),fbits(a),0x07060302u);}

#if defined(__has_builtin)
#if __has_builtin(__builtin_amdgcn_mfma_f32_16x16x16bf16_1k)
#define HAVE_MFMA16 1
#endif
#endif

#ifdef HAVE_MFMA16
// two packed-bf16 dwords -> bf16x4 operand (no unions: bit_cast of uint2)
static __device__ __forceinline__ bf16x4 mk4(unsigned lo, unsigned hi){
  uint2 t; t.x=lo; t.y=hi;
  return __builtin_bit_cast(bf16x4, t);
}
#endif

// Block barrier with LDS-drain only: does NOT wait vmcnt, so register-staged
// global prefetch loads remain in flight across it (T4).
static __device__ __forceinline__ void barrier_lgkm(){
  asm volatile("s_waitcnt lgkmcnt(0)" ::: "memory");
  __builtin_amdgcn_s_barrier();
  asm volatile("" ::: "memory");
}

__global__ __launch_bounds__(256,3) void anomaly_attn(
    const float* __restrict__ Q, const float* __restrict__ K,
    const float* __restrict__ V, const float* __restrict__ Sig,
    const float* __restrict__ Gate, float* __restrict__ Out)
{
  __shared__ unsigned short Klds[2][64*KST];   // 18432 B (double-buffered)
  __shared__ unsigned short Vlds[2][64*VST];   // 18432 B (V^T, granule-swizzled)
#ifndef HAVE_MFMA16
  __shared__ unsigned We[4][16][WST];          // 9216 B packed e pairs (Path B)
#endif

  const int tid=threadIdx.x, lane=tid&63, wid=tid>>6, q=lane>>4, c=lane&15;
  const int idx=blockIdx.x, bh=idx&127, t=7-(idx>>7), h=bh&7, b=bh>>3;
  const int l0w = t*64 + wid*16;            // wave's 16 l-rows: l = l0w + c
  const size_t bh_off = ((size_t)b*L_*H_ + h)*64;
  const float* __restrict__ Qb=Q+bh_off;
  const float* __restrict__ Kb=K+bh_off;
  const float* __restrict__ Vb=V+bh_off;

  const int kr=tid>>2, kcb=tid&3, srp=tid>>3, scb=tid&7;
  const int gp=(srp>>2)^scb, rpl=srp&3, vb0i=(gp<<3);  // V pack mapping
#ifndef HAVE_MFMA16
  const int swz = (c&3)<<3;                 // We column XOR swizzle (Path B)
#endif

  // per-thread staging base pointers (add s0*512 per tile)
  const float* __restrict__ vbase = Vb + (size_t)(2*srp)*512 + scb*8;
  const float* __restrict__ kbase = Kb + (size_t)kr*512 + kcb*16;

  // ---- prologue: load + pack tile 0 into buffer 0 (always live) ----
  {
    float4 a0=((const float4*)vbase)[0],       a1=((const float4*)vbase)[1];
    float4 b0=((const float4*)(vbase+512))[0], b1=((const float4*)(vbase+512))[1];
    float4 ka=((const float4*)kbase)[0], kb2=((const float4*)kbase)[1];
    float4 kc2=((const float4*)kbase)[2], kd2=((const float4*)kbase)[3];
    ((unsigned*)&Vlds[0][(scb*8+0)*VST+vb0i])[rpl]=pk2(a0.x,b0.x);
    ((unsigned*)&Vlds[0][(scb*8+1)*VST+vb0i])[rpl]=pk2(a0.y,b0.y);
    ((unsigned*)&Vlds[0][(scb*8+2)*VST+vb0i])[rpl]=pk2(a0.z,b0.z);
    ((unsigned*)&Vlds[0][(scb*8+3)*VST+vb0i])[rpl]=pk2(a0.w,b0.w);
    ((unsigned*)&Vlds[0][(scb*8+4)*VST+vb0i])[rpl]=pk2(a1.x,b1.x);
    ((unsigned*)&Vlds[0][(scb*8+5)*VST+vb0i])[rpl]=pk2(a1.y,b1.y);
    ((unsigned*)&Vlds[0][(scb*8+6)*VST+vb0i])[rpl]=pk2(a1.z,b1.z);
    ((unsigned*)&Vlds[0][(scb*8+7)*VST+vb0i])[rpl]=pk2(a1.w,b1.w);
    uint4 w0,w1;
    w0.x=pk2(ka.x,ka.y);   w0.y=pk2(ka.z,ka.w);
    w0.z=pk2(kb2.x,kb2.y); w0.w=pk2(kb2.z,kb2.w);
    w1.x=pk2(kc2.x,kc2.y); w1.y=pk2(kc2.z,kc2.w);
    w1.z=pk2(kd2.x,kd2.y); w1.w=pk2(kd2.z,kd2.w);
    uint4* dst=(uint4*)&Klds[0][kr*KST + kcb*16];
    dst[0]=w0; dst[1]=w1;
  }

  // ---- Q as B-operand frag: lane c -> l, quad*8+j -> e (for 16x16x32 QK) ----
  bf16x8 qf[2];
  {
    const float* qrow = Qb + (size_t)(l0w+c)*512;
    #pragma unroll
    for (int ks=0; ks<2; ++ks) {
      const float4 a = *(const float4*)(qrow + ks*32 + q*8);
      const float4 d4 = *(const float4*)(qrow + ks*32 + q*8 + 4);
      FR f;
      f.u[0]=pk2(a.x,a.y);  f.u[1]=pk2(a.z,a.w);
      f.u[2]=pk2(d4.x,d4.y); f.u[3]=pk2(d4.z,d4.w);
      qf[ks]=f.v;
    }
  }

  // ---- per-lane prior constants (row l = l0w + c) ----
  const float sgv = Sig[((size_t)b*L_ + l0w + c)*H_ + h];
  float sg = 1.f/(1.f+__expf(-5.f*sgv)) + 1e-5f;
  sg = exp2f(sg*1.5849625007211562f) - 1.f;          // 3^sg - 1
  const float invs = 0.3989422804014327f/sg;
  const float i2s2 = (0.5f/(sg*sg))*1.44269504088896f;

  float eP=0.f, pP=0.f;
  f32x4 accA[4], accB[4];
  #pragma unroll
  for (int n=0;n<4;++n){accA[n]=(f32x4)0.f;accB[n]=(f32x4)0.f;}

  barrier_lgkm();   // publish tile-0 buffers

#ifdef HAVE_MFMA16
  const int qh=q>>1, ql=(q&1)<<2;   // V b64 frag: granule half / dword pair
#endif

  for (int tile=0; tile<8; ++tile) {
    const int s0=tile*64, p=tile&1;
    const unsigned short* __restrict__ Krd=&Klds[p][0];
    const unsigned short* __restrict__ Vrd=&Vlds[p][0];
    const bool live = tile<=t, diag = tile==t;   // block-uniform
    const int delta = s0 - l0w;                  // wave-uniform
    const bool bk0 = (delta    >= -95) && (delta    <= 79);
    const bool bk1 = (delta+32 >= -95) && (delta+32 <= 79);

    // ---- issue tile+1 global loads NOW (within-iteration liveness, no
    //      loop-carried PHIs); consumed only at the pack below ----
    float4 sva0,sva1,svb0,svb1,ska,skb,skc,skd;
    bool live1=false, vneed1=false;
    if (tile<7) {
      const int d1=delta+64;
      live1 = (tile+1)<=t;
      const bool b0n = (d1    >= -95) && (d1    <= 79);
      const bool b1n = (d1+32 >= -95) && (d1+32 <= 79);
      vneed1 = live1 || b0n || b1n;              // block-uniform in value
      const float* vp = vbase + (size_t)(s0+64)*512;
      const float* kp = kbase + (size_t)(s0+64)*512;
      if (vneed1) {
        sva0=((const float4*)vp)[0];       sva1=((const float4*)vp)[1];
        svb0=((const float4*)(vp+512))[0]; svb1=((const float4*)(vp+512))[1];
      }
      if (live1) {
        ska=((const float4*)kp)[0]; skb=((const float4*)kp)[1];
        skc=((const float4*)kp)[2]; skd=((const float4*)kp)[3];
      }
    }
    asm volatile("" ::: "memory");   // pin prefetch issue before compute

#ifdef HAVE_MFMA16
    // ======== Path A: register-direct PV via 16x16x16 (no We LDS) ========
    int ntmax = -1;
    unsigned efu[4][2];              // packed exp'd scores, static indices only
    if (live) {
      ntmax = diag ? wid : 3;
      f32x4 sacc[4];
      #pragma unroll
      for (int nt=0;nt<4;++nt) if (nt<=ntmax) {
        f32x4 s=(f32x4)0.f;
        #pragma unroll
        for (int ks=0;ks<2;++ks){
          const bf16x8 kf=*(const bf16x8*)&Krd[(nt*16+c)*KST + ks*32 + q*8];
          s=__builtin_amdgcn_mfma_f32_16x16x32_bf16(kf,qf[ks],s,0,0,0); // A=K(m=s),B=Q(n=l)
        }
        sacc[nt]=s;
      }
      #pragma unroll
      for (int nt=0;nt<4;++nt) if (nt<=ntmax) {
        float ev[4];
        #pragma unroll
        for (int r=0;r<4;++r) ev[r]=exp2f(sacc[nt][r]*0.180336880110323f); // exp(s/8)
        if (diag && nt==wid) {                   // per-element causal mask
          #pragma unroll
          for (int r=0;r<4;++r) if (4*q+r > c) ev[r]=0.f;
        }
        #pragma unroll
        for (int r=0;r<4;++r) eP += tvf(ev[r]);  // sum == MFMA operand
        efu[nt][0]=pk2(ev[0],ev[1]); efu[nt][1]=pk2(ev[2],ev[3]);
      }
    }
    // PV: A = V^T (m=d,k=s), B = e/p (k=s=nt*16+q*4+j, n=l=c), one
    // ds_read_b64 per (nd,nt), acc via builtin (AGPR-allocatable).
    #pragma unroll
    for (int nt=0;nt<4;++nt) {
      const bool ea = live && (nt<=ntmax);
      const int dw = delta + nt*16;
      const bool pa = (dw >= -79) && (dw <= 79); // per-16-chunk prior band
      if (ea || pa) {
        unsigned pf0=0u, pf1=0u;
        if (pa) {
          float pv[4];
          #pragma unroll
          for (int j=0;j<4;++j){
            const float dd=(float)(c - nt*16 - q*4 - j - delta);  // l - s
            pv[j]=invs*exp2f(-dd*dd*i2s2);
            pP += tvf(pv[j]);
          }
          pf0=pk2(pv[0],pv[1]); pf1=pk2(pv[2],pv[3]);
        }
        #pragma unroll
        for (int nd=0;nd<4;++nd){
          const int d=nd*16+c;
          const int graw=(2*nt+qh)^(d>>3);
          const bf16x4 vf=*(const bf16x4*)&Vrd[d*VST + (graw<<3) + ql];
          if (ea) accA[nd]=__builtin_amdgcn_mfma_f32_16x16x16bf16_1k(vf,mk4(efu[nt][0],efu[nt][1]),accA[nd],0,0,0);
          if (pa) accB[nd]=__builtin_amdgcn_mfma_f32_16x16x16bf16_1k(vf,mk4(pf0,pf1),accB[nd],0,0,0);
        }
      }
    }
#else
    // ======== Path B (R15 verified): We LDS round-trip + 16x16x32 PV ========
    int ks2max = -1;
    if (live) {
      const int ntmax = diag ? wid : 3;
      ks2max = diag ? (wid>>1) : 1;
      f32x4 sacc[4];
      #pragma unroll
      for (int nt=0;nt<4;++nt) if (nt<=ntmax) {
        f32x4 s=(f32x4)0.f;
        #pragma unroll
        for (int ks=0;ks<2;++ks){
          const bf16x8 kf=*(const bf16x8*)&Krd[(nt*16+c)*KST + ks*32 + q*8];
          s=__builtin_amdgcn_mfma_f32_16x16x32_bf16(kf,qf[ks],s,0,0,0);
        }
        sacc[nt]=s;
      }
      #pragma unroll
      for (int nt=0;nt<4;++nt) {
        if (nt<=ntmax) {
          float ev[4];
          #pragma unroll
          for (int r=0;r<4;++r) ev[r]=exp2f(sacc[nt][r]*0.180336880110323f);
          if (diag && nt==wid) {
            #pragma unroll
            for (int r=0;r<4;++r) if (4*q+r > c) ev[r]=0.f;
          }
          #pragma unroll
          for (int r=0;r<4;++r) eP += tvf(ev[r]);
          uint2 w; w.x=pk2(ev[0],ev[1]); w.y=pk2(ev[2],ev[3]);
          *(uint2*)&We[wid][c][(nt*8+2*q)^swz]=w;
        } else if (nt <= 2*ks2max+1) {
          uint2 zz; zz.x=0u; zz.y=0u;
          *(uint2*)&We[wid][c][(nt*8+2*q)^swz]=zz;
        }
      }
    }
    asm volatile("s_waitcnt lgkmcnt(0)" ::: "memory");
    FR ef[2], pf[2];
    #pragma unroll
    for (int k2=0;k2<2;++k2){
      if (k2<=ks2max) ef[k2].q4 = *(const uint4*)&We[wid][c][(k2*16+4*q)^swz];
      if (k2 ? bk1 : bk0) {
        float pv[8];
        #pragma unroll
        for (int j=0;j<8;++j){
          const float dd=(float)(c - k2*32 - q*8 - j - delta);
          pv[j]=invs*exp2f(-dd*dd*i2s2);
          pP += tvf(pv[j]);
        }
        pf[k2].u[0]=pk2(pv[0],pv[1]); pf[k2].u[1]=pk2(pv[2],pv[3]);
        pf[k2].u[2]=pk2(pv[4],pv[5]); pf[k2].u[3]=pk2(pv[6],pv[7]);
      }
    }
    #pragma unroll
    for (int nd=0;nd<4;++nd){
      const int d=nd*16+c, dg7=(d>>3)&7;
      #pragma unroll
      for (int k2=0;k2<2;++k2){
        const bool pb = k2 ? bk1 : bk0;
        if (k2<=ks2max || pb) {
          const int g2i=((k2<<2)+q)^dg7;
          const bf16x8 vf=*(const bf16x8*)&Vrd[d*VST + (g2i<<3)];
          if (k2<=ks2max) accA[nd]=__builtin_amdgcn_mfma_f32_16x16x32_bf16(vf,ef[k2].v,accA[nd],0,0,0);
          if (pb)         accB[nd]=__builtin_amdgcn_mfma_f32_16x16x32_bf16(vf,pf[k2].v,accB[nd],0,0,0);
        }
      }
    }
#endif

    // ---- write-late: pack tile+1 into the OTHER buffer (no reader this
    //      iteration; vmcnt wait lands here, covered by the compute above) ----
    if (tile<7) {
      const int pn=p^1;
      if (vneed1) {
        ((unsigned*)&Vlds[pn][(scb*8+0)*VST+vb0i])[rpl]=pk2(sva0.x,svb0.x);
        ((unsigned*)&Vlds[pn][(scb*8+1)*VST+vb0i])[rpl]=pk2(sva0.y,svb0.y);
        ((unsigned*)&Vlds[pn][(scb*8+2)*VST+vb0i])[rpl]=pk2(sva0.z,svb0.z);
        ((unsigned*)&Vlds[pn][(scb*8+3)*VST+vb0i])[rpl]=pk2(sva0.w,svb0.w);
        ((unsigned*)&Vlds[pn][(scb*8+4)*VST+vb0i])[rpl]=pk2(sva1.x,svb1.x);
        ((unsigned*)&Vlds[pn][(scb*8+5)*VST+vb0i])[rpl]=pk2(sva1.y,svb1.y);
        ((unsigned*)&Vlds[pn][(scb*8+6)*VST+vb0i])[rpl]=pk2(sva1.z,svb1.z);
        ((unsigned*)&Vlds[pn][(scb*8+7)*VST+vb0i])[rpl]=pk2(sva1.w,svb1.w);
      }
      if (live1) {
        uint4 w0,w1;
        w0.x=pk2(ska.x,ska.y); w0.y=pk2(ska.z,ska.w);
        w0.z=pk2(skb.x,skb.y); w0.w=pk2(skb.z,skb.w);
        w1.x=pk2(skc.x,skc.y); w1.y=pk2(skc.z,skc.w);
        w1.z=pk2(skd.x,skd.y); w1.w=pk2(skd.z,skd.w);
        uint4* dst=(uint4*)&Klds[pn][kr*KST + kcb*16];
        dst[0]=w0; dst[1]=w1;
      }
    }

    barrier_lgkm();   // single per-iteration barrier: publishes tile+1 packs;
                      // orders this tile's LDS reads before next-next overwrite
  }

  // ---- epilogue: quad reduce, per-lane scalars, float4 stores ----
  eP += __shfl_xor(eP,16,64); eP += __shfl_xor(eP,32,64);
  pP += __shfl_xor(pP,16,64); pP += __shfl_xor(pP,32,64);
  float g=Gate[h]; g=1.f/(1.f+__expf(-g));
  const float cA=g/eP;                       // E>0 (diagonal always live)
  const float cB=(1.f-g)/(pP+1e-8f);
  const float Sf=g+(1.f-g)*(pP/(pP+1e-8f));
  const float nf=1.f/(Sf+1e-8f);
  #pragma unroll
  for (int nd=0;nd<4;++nd){
    float4 o;
    o.x=(cA*accA[nd][0]+cB*accB[nd][0])*nf;
    o.y=(cA*accA[nd][1]+cB*accB[nd][1])*nf;
    o.z=(cA*accA[nd][2]+cB*accB[nd][2])*nf;
    o.w=(cA*accA[nd][3]+cB*accB[nd][3])*nf;
    *(float4*)&Out[bh_off + (size_t)(l0w+c)*512 + nd*16 + 4*q] = o;
  }
}

extern "C" void kernel_launch(void* const* d_in, const int* in_sizes, int n_in,
                              void* d_out, int out_size, void* d_ws, size_t ws_size,
                              hipStream_t stream) {
    const float* Q    = (const float*)d_in[0];
    const float* K    = (const float*)d_in[1];
    const float* V    = (const float*)d_in[2];
    const float* Sig  = (const float*)d_in[3];
    const float* Gate = (const float*)d_in[4];
    // d_in[5] = attn_mask: deterministic causal triu — not read.
    float* Out = (float*)d_out;

    dim3 grid(8 * B_ * H_);   // 1024 blocks: bh = idx&127 (XCD-affine), t reversed
    anomaly_attn<<<grid, 256, 0, stream>>>(Q, K, V, Sig, Gate, Out);
}